// Round 2
// baseline (266.075 us; speedup 1.0000x reference)
//
#include <hip/hip_runtime.h>
#include <hip/hip_bf16.h>
#include <cstdint>
#include <cstddef>

// MyBaseRNN: out[t,b,h] = tanh( x[t,b,:]·W[h,:] + ib[h] + h0[b,:]·U[h,:] + hb[h] )
// hidden = out[T-1].  GEMM: M=131072, N=512, K=512, A=x (MxK), B=W (NxK).

#define T_LEN 2048
#define BATCH 64
#define ISZ 512
#define HSZ 512
#define MTOT (T_LEN * BATCH) /* 131072 */

#define BM 128
#define BN 128
#define BK 64
#define NMT (MTOT / BM) /* 1024 m-tiles */

typedef __attribute__((ext_vector_type(8))) __bf16 bf16x8;
typedef __attribute__((ext_vector_type(4))) __bf16 bf16x4;
typedef __attribute__((ext_vector_type(4))) float f32x4;

#define GLOBAL_AS __attribute__((address_space(1)))
#define LDS_AS __attribute__((address_space(3)))

__device__ __forceinline__ float fast_tanh(float v) {
    float e = __expf(2.0f * v);
    return 1.0f - 2.0f / (e + 1.0f);
}

// ---------- Kernel 1: W (fp32, HxI row-major) -> bf16 ----------
__global__ __launch_bounds__(256) void convw_kernel(const float* __restrict__ W,
                                                    __bf16* __restrict__ Wbf) {
    int i = blockIdx.x * 256 + threadIdx.x;
    f32x4 f = ((const f32x4*)W)[i];
    bf16x4 v;
    v[0] = (__bf16)f[0]; v[1] = (__bf16)f[1];
    v[2] = (__bf16)f[2]; v[3] = (__bf16)f[3];
    ((bf16x4*)Wbf)[i] = v;
}

// ---------- Kernel 2: uh[b][h] = h0[b,:]·U[h,:] + hb[h] + ib[h] (fp32 exact) ----------
__global__ __launch_bounds__(512) void uh_kernel(const float* __restrict__ prev,
                                                 const float* __restrict__ U,
                                                 const float* __restrict__ hb,
                                                 const float* __restrict__ ib,
                                                 float* __restrict__ uh) {
    __shared__ float sp[HSZ];
    int b = blockIdx.x, h = threadIdx.x;
    sp[h] = prev[b * HSZ + h];
    __syncthreads();
    const float* urow = U + (size_t)h * HSZ;
    float acc = 0.f;
#pragma unroll 4
    for (int i = 0; i < HSZ; i += 4) {
        f32x4 u4 = *(const f32x4*)(urow + i);
        acc += u4[0] * sp[i] + u4[1] * sp[i + 1] + u4[2] * sp[i + 2] + u4[3] * sp[i + 3];
    }
    uh[b * HSZ + h] = acc + hb[h] + ib[h];
}

// ---------- Kernel 3: GEMM + bias + tanh (+ fused hidden copy) ----------
// 128x128x(BK=64), 4 waves (2x2), 16x16x32 bf16 MFMA, swapped operands.
// Double-buffered LDS, XOR-swizzled (T2): byte col ^= (row&7)<<4.
__global__ __launch_bounds__(256) void gemm_tanh_kernel(
        const float* __restrict__ x, const __bf16* __restrict__ Wbf,
        const float* __restrict__ uh, float* __restrict__ out,
        float* __restrict__ hid) {
    __shared__ __attribute__((aligned(16))) __bf16 sA[2][BM * BK]; // 2x16KB
    __shared__ __attribute__((aligned(16))) __bf16 sB[2][BN * BK]; // 2x16KB

    // XCD-bijective swizzle: nwg=4096 (%8==0), cpx=512.
    int orig = blockIdx.x;
    int wg = (orig & 7) * 512 + (orig >> 3);
    int mt = wg >> 2, nt = wg & 3;

    int tid = threadIdx.x;
    int lane = tid & 63, wid = tid >> 6;
    int wr = wid >> 1, wc = wid & 1;
    int l15 = lane & 15, l4 = lane >> 4;

    const size_t m0 = (size_t)mt * BM;
    const int n0 = nt * BN;

    f32x4 acc[4][4] = {};
    f32x4 aPre[8];

    // --- B stage: global_load_lds width-16, pre-swizzled global source ---
    auto stageB = [&](int buf, int ks) {
#pragma unroll
        for (int j = 0; j < 4; ++j) {
            int chunk = wid * 4 + j;                 // 0..15 (1KB each)
            int row = chunk * 8 + (lane >> 3);       // row this lane feeds
            int cb = ((lane & 7) ^ (lane >> 3)) << 4; // swizzled source col-byte
            const __bf16* g = Wbf + (size_t)(n0 + row) * ISZ + ks + (cb >> 1);
            __builtin_amdgcn_global_load_lds((const GLOBAL_AS uint32_t*)g,
                (LDS_AS uint32_t*)((char*)sB[buf] + chunk * 1024), 16, 0, 0);
        }
    };
    // --- A: global fp32 -> regs ---
    auto loadA = [&](int ks) {
#pragma unroll
        for (int it = 0; it < 4; ++it) {
            int p = it * 256 + tid;
            int row = p >> 3, pc = p & 7;
            const float* src = x + (m0 + row) * ISZ + ks + pc * 8;
            aPre[2 * it]     = *(const f32x4*)src;
            aPre[2 * it + 1] = *(const f32x4*)(src + 4);
        }
    };
    // --- A: regs -> bf16 LDS (swizzled write) ---
    auto writeA = [&](int buf) {
#pragma unroll
        for (int it = 0; it < 4; ++it) {
            int p = it * 256 + tid;
            int row = p >> 3, pc = p & 7;
            f32x4 f0 = aPre[2 * it], f1 = aPre[2 * it + 1];
            bf16x8 v;
            v[0] = (__bf16)f0[0]; v[1] = (__bf16)f0[1];
            v[2] = (__bf16)f0[2]; v[3] = (__bf16)f0[3];
            v[4] = (__bf16)f1[0]; v[5] = (__bf16)f1[1];
            v[6] = (__bf16)f1[2]; v[7] = (__bf16)f1[3];
            int cb = (pc * 16) ^ ((row & 7) << 4);
            *(bf16x8*)((char*)sA[buf] + row * 128 + cb) = v;
        }
    };
    // --- compute one K-tile: ds_read (swizzled) + 32 MFMA, swapped operands ---
    auto compute = [&](int buf) {
#pragma unroll
        for (int kk = 0; kk < 2; ++kk) {
            bf16x8 af[4], bfr[4];
#pragma unroll
            for (int mi = 0; mi < 4; ++mi) {
                int row = wr * 64 + mi * 16 + l15;
                int cb = (kk * 64 + l4 * 16) ^ ((row & 7) << 4);
                af[mi] = *(const bf16x8*)((const char*)sA[buf] + row * 128 + cb);
            }
#pragma unroll
            for (int ni = 0; ni < 4; ++ni) {
                int row = wc * 64 + ni * 16 + l15;
                int cb = (kk * 64 + l4 * 16) ^ ((row & 7) << 4);
                bfr[ni] = *(const bf16x8*)((const char*)sB[buf] + row * 128 + cb);
            }
#pragma unroll
            for (int mi = 0; mi < 4; ++mi)
#pragma unroll
                for (int ni = 0; ni < 4; ++ni)
                    acc[mi][ni] = __builtin_amdgcn_mfma_f32_16x16x32_bf16(
                        bfr[ni], af[mi], acc[mi][ni], 0, 0, 0);
        }
    };

    // prologue: tile 0
    stageB(0, 0);
    loadA(0);
    writeA(0);
    __syncthreads();

#pragma unroll 2
    for (int t = 0; t < 7; ++t) {
        int cur = t & 1, nxt = cur ^ 1;
        int ks = (t + 1) * BK;
        loadA(ks);        // issue next A (global->reg) early
        stageB(nxt, ks);  // issue next B (global->LDS) early
        compute(cur);     // ds_read + MFMA on current
        writeA(nxt);      // vmcnt-wait lands here, cvt + ds_write
        __syncthreads();  // one barrier per K-step
    }
    compute(1);           // tile 7 lives in buffer 1

    // ---- epilogue: + uh, tanh, dwordx4 stores. Swapped-operand D layout:
    // col (lane&15) = m-local, row ((lane>>4)*4+r) = n-local -> r runs over n.
    bool lastTile = (mt == NMT - 1);
#pragma unroll
    for (int mi = 0; mi < 4; ++mi) {
        int ml = wr * 64 + mi * 16 + l15;
        size_t m = m0 + ml;
        int bb = ml & 63; // batch index (m0 multiple of 128)
#pragma unroll
        for (int ni = 0; ni < 4; ++ni) {
            int nb = n0 + wc * 64 + ni * 16 + l4 * 4;
            f32x4 u4 = *(const f32x4*)&uh[bb * HSZ + nb];
            f32x4 v;
#pragma unroll
            for (int r = 0; r < 4; ++r) v[r] = fast_tanh(acc[mi][ni][r] + u4[r]);
            *(f32x4*)&out[m * HSZ + nb] = v;
            if (lastTile && ml >= BM - BATCH)
                *(f32x4*)&hid[(size_t)(ml - (BM - BATCH)) * HSZ + nb] = v;
        }
    }
}

extern "C" void kernel_launch(void* const* d_in, const int* in_sizes, int n_in,
                              void* d_out, int out_size, void* d_ws, size_t ws_size,
                              hipStream_t stream) {
    const float* x  = (const float*)d_in[0];
    const float* ph = (const float*)d_in[1];
    const float* W  = (const float*)d_in[2];
    const float* U  = (const float*)d_in[3];
    const float* hb = (const float*)d_in[4];
    const float* ib = (const float*)d_in[5];
    float* out = (float*)d_out;
    float* hid = out + (size_t)MTOT * HSZ;

    __bf16* Wbf = (__bf16*)d_ws;                      // 512 KB
    float* uh   = (float*)((char*)d_ws + 512 * 1024); // 128 KB

    hipLaunchKernelGGL(convw_kernel, dim3(256), dim3(256), 0, stream, W, Wbf);
    hipLaunchKernelGGL(uh_kernel, dim3(64), dim3(512), 0, stream, ph, U, hb, ib, uh);
    hipLaunchKernelGGL(gemm_tanh_kernel, dim3(4096), dim3(256), 0, stream,
                       x, Wbf, uh, out, hid);
}

// Round 3
// 240.529 us; speedup vs baseline: 1.1062x; 1.1062x over previous
//
#include <hip/hip_runtime.h>
#include <hip/hip_bf16.h>
#include <cstdint>
#include <cstddef>

// MyBaseRNN: out[t,b,h] = tanh( x[t,b,:]·W[h,:] + ib[h] + h0[b,:]·U[h,:] + hb[h] )
// hidden = out[T-1].  GEMM: M=131072, N=512, K=512, A=x (MxK), B=W (NxK).
// R3: R1 loop structure (single-buf 32KB LDS -> 5 blocks/CU) + R2 swizzle
// (0 bank conflicts) + early A-load issue + fused epilogue.

#define T_LEN 2048
#define BATCH 64
#define ISZ 512
#define HSZ 512
#define MTOT (T_LEN * BATCH) /* 131072 */

#define BM 128
#define BN 128
#define BK 64
#define NMT (MTOT / BM) /* 1024 m-tiles */

typedef __attribute__((ext_vector_type(8))) __bf16 bf16x8;
typedef __attribute__((ext_vector_type(4))) __bf16 bf16x4;
typedef __attribute__((ext_vector_type(4))) float f32x4;

#define GLOBAL_AS __attribute__((address_space(1)))
#define LDS_AS __attribute__((address_space(3)))

__device__ __forceinline__ float fast_tanh(float v) {
    float e = __expf(2.0f * v);
    return 1.0f - 2.0f / (e + 1.0f);
}

// ---------- Kernel 1: fused W->bf16 convert (blocks 0..127) + uh (blocks 128..191) ----
__global__ __launch_bounds__(512) void prep_kernel(const float* __restrict__ W,
                                                   __bf16* __restrict__ Wbf,
                                                   const float* __restrict__ prev,
                                                   const float* __restrict__ U,
                                                   const float* __restrict__ hb,
                                                   const float* __restrict__ ib,
                                                   float* __restrict__ uh) {
    if (blockIdx.x < 128) {
        int i = blockIdx.x * 512 + threadIdx.x; // 65536 f32x4 total
        f32x4 f = ((const f32x4*)W)[i];
        bf16x4 v;
        v[0] = (__bf16)f[0]; v[1] = (__bf16)f[1];
        v[2] = (__bf16)f[2]; v[3] = (__bf16)f[3];
        ((bf16x4*)Wbf)[i] = v;
    } else {
        __shared__ float sp[HSZ];
        int b = blockIdx.x - 128, h = threadIdx.x;
        sp[h] = prev[b * HSZ + h];
        __syncthreads();
        const float* urow = U + (size_t)h * HSZ;
        float acc = 0.f;
#pragma unroll 4
        for (int i = 0; i < HSZ; i += 4) {
            f32x4 u4 = *(const f32x4*)(urow + i);
            acc += u4[0] * sp[i] + u4[1] * sp[i + 1] + u4[2] * sp[i + 2] + u4[3] * sp[i + 3];
        }
        uh[b * HSZ + h] = acc + hb[h] + ib[h];
    }
}

// ---------- Kernel 2: GEMM + bias + tanh (+ fused hidden copy) ----------
// 128x128x(BK=64), 4 waves (2x2), 16x16x32 bf16 MFMA, swapped operands.
// SINGLE-buffered LDS (32 KB total), XOR-swizzled: byte col ^= (row&7)<<4.
__global__ __launch_bounds__(256) void gemm_tanh_kernel(
        const float* __restrict__ x, const __bf16* __restrict__ Wbf,
        const float* __restrict__ uh, float* __restrict__ out,
        float* __restrict__ hid) {
    __shared__ __attribute__((aligned(16))) __bf16 sA[BM * BK]; // 16 KB
    __shared__ __attribute__((aligned(16))) __bf16 sB[BN * BK]; // 16 KB

    // XCD-bijective swizzle: nwg=4096 (%8==0), cpx=512. 4 n-tiles of an
    // m-panel are consecutive on one XCD -> x panel fetched once per XCD.
    int orig = blockIdx.x;
    int wg = (orig & 7) * 512 + (orig >> 3);
    int mt = wg >> 2, nt = wg & 3;

    int tid = threadIdx.x;
    int lane = tid & 63, wid = tid >> 6;
    int wr = wid >> 1, wc = wid & 1;
    int l15 = lane & 15, l4 = lane >> 4;

    const size_t m0 = (size_t)mt * BM;
    const int n0 = nt * BN;

    f32x4 acc[4][4] = {};
    f32x4 aPre[8];

    // --- B stage: global_load_lds width-16, pre-swizzled global source ---
    auto stageB = [&](int ks) {
#pragma unroll
        for (int j = 0; j < 4; ++j) {
            int chunk = wid * 4 + j;                  // 0..15 (1KB each)
            int row = chunk * 8 + (lane >> 3);        // dest row (linear)
            int cb = ((lane & 7) ^ (lane >> 3)) << 4; // swizzled source col-byte
            const __bf16* g = Wbf + (size_t)(n0 + row) * ISZ + ks + (cb >> 1);
            __builtin_amdgcn_global_load_lds((const GLOBAL_AS uint32_t*)g,
                (LDS_AS uint32_t*)((char*)sB + chunk * 1024), 16, 0, 0);
        }
    };
    // --- A: global fp32 -> regs (issue early; consumed by writeA) ---
    auto loadA = [&](int ks) {
#pragma unroll
        for (int it = 0; it < 4; ++it) {
            int p = it * 256 + tid;
            int row = p >> 3, pc = p & 7;
            const float* src = x + (m0 + row) * ISZ + ks + pc * 8;
            aPre[2 * it]     = *(const f32x4*)src;
            aPre[2 * it + 1] = *(const f32x4*)(src + 4);
        }
    };
    // --- A: regs -> bf16 LDS (swizzled write) ---
    auto writeA = [&]() {
#pragma unroll
        for (int it = 0; it < 4; ++it) {
            int p = it * 256 + tid;
            int row = p >> 3, pc = p & 7;
            f32x4 f0 = aPre[2 * it], f1 = aPre[2 * it + 1];
            bf16x8 v;
            v[0] = (__bf16)f0[0]; v[1] = (__bf16)f0[1];
            v[2] = (__bf16)f0[2]; v[3] = (__bf16)f0[3];
            v[4] = (__bf16)f1[0]; v[5] = (__bf16)f1[1];
            v[6] = (__bf16)f1[2]; v[7] = (__bf16)f1[3];
            int cb = (pc * 16) ^ ((row & 7) << 4);
            *(bf16x8*)((char*)sA + row * 128 + cb) = v;
        }
    };
    // --- compute one K-tile: swizzled ds_read + 32 MFMA, swapped operands ---
    auto compute = [&]() {
#pragma unroll
        for (int kk = 0; kk < 2; ++kk) {
            bf16x8 af[4], bfr[4];
#pragma unroll
            for (int mi = 0; mi < 4; ++mi) {
                int row = wr * 64 + mi * 16 + l15;
                int cb = (kk * 64 + l4 * 16) ^ ((row & 7) << 4);
                af[mi] = *(const bf16x8*)((const char*)sA + row * 128 + cb);
            }
#pragma unroll
            for (int ni = 0; ni < 4; ++ni) {
                int row = wc * 64 + ni * 16 + l15;
                int cb = (kk * 64 + l4 * 16) ^ ((row & 7) << 4);
                bfr[ni] = *(const bf16x8*)((const char*)sB + row * 128 + cb);
            }
#pragma unroll
            for (int mi = 0; mi < 4; ++mi)
#pragma unroll
                for (int ni = 0; ni < 4; ++ni)
                    acc[mi][ni] = __builtin_amdgcn_mfma_f32_16x16x32_bf16(
                        bfr[ni], af[mi], acc[mi][ni], 0, 0, 0);
        }
    };

    // prologue: tile 0
    loadA(0);
    stageB(0);
    writeA();
    __syncthreads();

#pragma unroll 1
    for (int t = 0; t < 8; ++t) {
        if (t < 7) loadA((t + 1) * BK); // issue next A globals under compute
        compute();
        if (t < 7) {
            __syncthreads();            // all waves done reading sA/sB
            stageB((t + 1) * BK);       // issue B gload_lds first (async)
            writeA();                   // cvt + ds_write while B flies
            __syncthreads();            // next tile visible
        }
    }

    // ---- epilogue: + uh, tanh, dwordx4 stores. Swapped-operand D layout:
    // col (lane&15) = m-local, row ((lane>>4)*4+r) = n-local -> r runs over n.
    bool lastTile = (mt == NMT - 1);
#pragma unroll
    for (int mi = 0; mi < 4; ++mi) {
        int ml = wr * 64 + mi * 16 + l15;
        size_t m = m0 + ml;
        int bb = ml & 63; // batch index (m0 multiple of 128)
#pragma unroll
        for (int ni = 0; ni < 4; ++ni) {
            int nb = n0 + wc * 64 + ni * 16 + l4 * 4;
            f32x4 u4 = *(const f32x4*)&uh[bb * HSZ + nb];
            f32x4 v;
#pragma unroll
            for (int r = 0; r < 4; ++r) v[r] = fast_tanh(acc[mi][ni][r] + u4[r]);
            *(f32x4*)&out[m * HSZ + nb] = v;
            if (lastTile && ml >= BM - BATCH)
                *(f32x4*)&hid[(size_t)(ml - (BM - BATCH)) * HSZ + nb] = v;
        }
    }
}

extern "C" void kernel_launch(void* const* d_in, const int* in_sizes, int n_in,
                              void* d_out, int out_size, void* d_ws, size_t ws_size,
                              hipStream_t stream) {
    const float* x  = (const float*)d_in[0];
    const float* ph = (const float*)d_in[1];
    const float* W  = (const float*)d_in[2];
    const float* U  = (const float*)d_in[3];
    const float* hb = (const float*)d_in[4];
    const float* ib = (const float*)d_in[5];
    float* out = (float*)d_out;
    float* hid = out + (size_t)MTOT * HSZ;

    __bf16* Wbf = (__bf16*)d_ws;                      // 512 KB
    float* uh   = (float*)((char*)d_ws + 512 * 1024); // 128 KB

    hipLaunchKernelGGL(prep_kernel, dim3(192), dim3(512), 0, stream,
                       W, Wbf, ph, U, hb, ib, uh);
    hipLaunchKernelGGL(gemm_tanh_kernel, dim3(4096), dim3(256), 0, stream,
                       x, Wbf, uh, out, hid);
}

// Round 4
// 236.576 us; speedup vs baseline: 1.1247x; 1.0167x over previous
//
#include <hip/hip_runtime.h>
#include <hip/hip_bf16.h>
#include <cstdint>
#include <cstddef>

// MyBaseRNN: out[t,b,h] = tanh( x[t,b,:]·W[h,:] + ib[h] + h0[b,:]·U[h,:] + hb[h] )
// hidden = out[T-1].  GEMM: M=131072, N=512, K=512, A=x (MxK), B=W (NxK).
// R4 = R1 transient-staging structure (VGPR 64 -> 4 waves/SIMD) + R2/R3
// zero-conflict XOR swizzle + stageB-first ordering + fused hid epilogue.
// Evidence: R1 64VGPR/42%occ/212us beat R3 100VGPR/21%occ/227us -> latency-
// bound, occupancy is the lever; swizzle gives 0 conflicts at no LDS cost.

#define T_LEN 2048
#define BATCH 64
#define ISZ 512
#define HSZ 512
#define MTOT (T_LEN * BATCH) /* 131072 */

#define BM 128
#define BN 128
#define BK 64
#define NMT (MTOT / BM) /* 1024 m-tiles */

typedef __attribute__((ext_vector_type(8))) __bf16 bf16x8;
typedef __attribute__((ext_vector_type(4))) __bf16 bf16x4;
typedef __attribute__((ext_vector_type(4))) float f32x4;

#define GLOBAL_AS __attribute__((address_space(1)))
#define LDS_AS __attribute__((address_space(3)))

__device__ __forceinline__ float fast_tanh(float v) {
    float e = __expf(2.0f * v);
    return 1.0f - 2.0f / (e + 1.0f);
}

// ---------- Kernel 1: fused W->bf16 convert (blocks 0..127) + uh (blocks 128..191) ----
__global__ __launch_bounds__(512) void prep_kernel(const float* __restrict__ W,
                                                   __bf16* __restrict__ Wbf,
                                                   const float* __restrict__ prev,
                                                   const float* __restrict__ U,
                                                   const float* __restrict__ hb,
                                                   const float* __restrict__ ib,
                                                   float* __restrict__ uh) {
    if (blockIdx.x < 128) {
        int i = blockIdx.x * 512 + threadIdx.x; // 65536 f32x4 total
        f32x4 f = ((const f32x4*)W)[i];
        bf16x4 v;
        v[0] = (__bf16)f[0]; v[1] = (__bf16)f[1];
        v[2] = (__bf16)f[2]; v[3] = (__bf16)f[3];
        ((bf16x4*)Wbf)[i] = v;
    } else {
        __shared__ float sp[HSZ];
        int b = blockIdx.x - 128, h = threadIdx.x;
        sp[h] = prev[b * HSZ + h];
        __syncthreads();
        const float* urow = U + (size_t)h * HSZ;
        float acc = 0.f;
#pragma unroll 4
        for (int i = 0; i < HSZ; i += 4) {
            f32x4 u4 = *(const f32x4*)(urow + i);
            acc += u4[0] * sp[i] + u4[1] * sp[i + 1] + u4[2] * sp[i + 2] + u4[3] * sp[i + 3];
        }
        uh[b * HSZ + h] = acc + hb[h] + ib[h];
    }
}

// ---------- Kernel 2: GEMM + bias + tanh (+ fused hidden copy) ----------
// 128x128x(BK=64), 4 waves (2x2), 16x16x32 bf16 MFMA, swapped operands.
// Single-buffered 32 KB LDS, XOR swizzle: byte col ^= (row&7)<<4.
// __launch_bounds__(256,4): 4 waves/SIMD -> 128 unified regs = 64 arch + 64 acc.
__global__ __launch_bounds__(256, 4) void gemm_tanh_kernel(
        const float* __restrict__ x, const __bf16* __restrict__ Wbf,
        const float* __restrict__ uh, float* __restrict__ out,
        float* __restrict__ hid) {
    __shared__ __attribute__((aligned(16))) __bf16 sA[BM * BK]; // 16 KB
    __shared__ __attribute__((aligned(16))) __bf16 sB[BN * BK]; // 16 KB

    // XCD-bijective swizzle: nwg=4096 (%8==0), cpx=512. 4 n-tiles of an
    // m-panel consecutive on one XCD -> x panel fetched ~once per XCD.
    int orig = blockIdx.x;
    int wg = (orig & 7) * 512 + (orig >> 3);
    int mt = wg >> 2, nt = wg & 3;

    int tid = threadIdx.x;
    int lane = tid & 63, wid = tid >> 6;
    int wr = wid >> 1, wc = wid & 1;
    int l15 = lane & 15, l4 = lane >> 4;

    const size_t m0 = (size_t)mt * BM;
    const int n0 = nt * BN;

    f32x4 acc[4][4] = {};

#pragma unroll 1
    for (int t = 0; t < 8; ++t) {
        int ks = t * BK;
        // ---- stage B first: async global_load_lds, pre-swizzled source ----
#pragma unroll
        for (int j = 0; j < 4; ++j) {
            int chunk = wid * 4 + j;                  // 0..15 (1KB each)
            int row = chunk * 8 + (lane >> 3);        // dest row (linear)
            int cb = ((lane & 7) ^ (lane >> 3)) << 4; // swizzled source col-byte
            const __bf16* g = Wbf + (size_t)(n0 + row) * ISZ + ks + (cb >> 1);
            __builtin_amdgcn_global_load_lds((const GLOBAL_AS uint32_t*)g,
                (LDS_AS uint32_t*)((char*)sB + chunk * 1024), 16, 0, 0);
        }
        // ---- stage A: fp32 load -> cvt -> swizzled LDS write (transient) ----
#pragma unroll
        for (int it = 0; it < 4; ++it) {
            int p = it * 256 + tid;
            int row = p >> 3, pc = p & 7;
            const float* src = x + (m0 + row) * ISZ + ks + pc * 8;
            f32x4 f0 = *(const f32x4*)src;
            f32x4 f1 = *(const f32x4*)(src + 4);
            bf16x8 v;
            v[0] = (__bf16)f0[0]; v[1] = (__bf16)f0[1];
            v[2] = (__bf16)f0[2]; v[3] = (__bf16)f0[3];
            v[4] = (__bf16)f1[0]; v[5] = (__bf16)f1[1];
            v[6] = (__bf16)f1[2]; v[7] = (__bf16)f1[3];
            int cb = (pc * 16) ^ ((row & 7) << 4);
            *(bf16x8*)((char*)sA + row * 128 + cb) = v;
        }
        __syncthreads();
        // ---- compute: 2 k-chunks, swizzled ds_read + 16 MFMA each ----
#pragma unroll
        for (int kk = 0; kk < 2; ++kk) {
            bf16x8 af[4], bfr[4];
#pragma unroll
            for (int mi = 0; mi < 4; ++mi) {
                int row = wr * 64 + mi * 16 + l15;
                int cb = (kk * 64 + l4 * 16) ^ ((row & 7) << 4);
                af[mi] = *(const bf16x8*)((const char*)sA + row * 128 + cb);
            }
#pragma unroll
            for (int ni = 0; ni < 4; ++ni) {
                int row = wc * 64 + ni * 16 + l15;
                int cb = (kk * 64 + l4 * 16) ^ ((row & 7) << 4);
                bfr[ni] = *(const bf16x8*)((const char*)sB + row * 128 + cb);
            }
#pragma unroll
            for (int mi = 0; mi < 4; ++mi)
#pragma unroll
                for (int ni = 0; ni < 4; ++ni)
                    acc[mi][ni] = __builtin_amdgcn_mfma_f32_16x16x32_bf16(
                        bfr[ni], af[mi], acc[mi][ni], 0, 0, 0);
        }
        if (t < 7) __syncthreads();
    }

    // ---- epilogue: + uh, tanh, dwordx4 stores. Swapped-operand D layout:
    // col (lane&15) = m-local, row ((lane>>4)*4+r) = n-local -> r runs over n.
    bool lastTile = (mt == NMT - 1);
#pragma unroll
    for (int mi = 0; mi < 4; ++mi) {
        int ml = wr * 64 + mi * 16 + l15;
        size_t m = m0 + ml;
        int bb = ml & 63; // batch index (m0 multiple of 128)
#pragma unroll
        for (int ni = 0; ni < 4; ++ni) {
            int nb = n0 + wc * 64 + ni * 16 + l4 * 4;
            f32x4 u4 = *(const f32x4*)&uh[bb * HSZ + nb];
            f32x4 v;
#pragma unroll
            for (int r = 0; r < 4; ++r) v[r] = fast_tanh(acc[mi][ni][r] + u4[r]);
            *(f32x4*)&out[m * HSZ + nb] = v;
            if (lastTile && ml >= BM - BATCH)
                *(f32x4*)&hid[(size_t)(ml - (BM - BATCH)) * HSZ + nb] = v;
        }
    }
}

extern "C" void kernel_launch(void* const* d_in, const int* in_sizes, int n_in,
                              void* d_out, int out_size, void* d_ws, size_t ws_size,
                              hipStream_t stream) {
    const float* x  = (const float*)d_in[0];
    const float* ph = (const float*)d_in[1];
    const float* W  = (const float*)d_in[2];
    const float* U  = (const float*)d_in[3];
    const float* hb = (const float*)d_in[4];
    const float* ib = (const float*)d_in[5];
    float* out = (float*)d_out;
    float* hid = out + (size_t)MTOT * HSZ;

    __bf16* Wbf = (__bf16*)d_ws;                      // 512 KB
    float* uh   = (float*)((char*)d_ws + 512 * 1024); // 128 KB

    hipLaunchKernelGGL(prep_kernel, dim3(192), dim3(512), 0, stream,
                       W, Wbf, ph, U, hb, ib, uh);
    hipLaunchKernelGGL(gemm_tanh_kernel, dim3(4096), dim3(256), 0, stream,
                       x, Wbf, uh, out, hid);
}